// Round 4
// baseline (578.281 us; speedup 1.0000x reference)
//
#include <hip/hip_runtime.h>
#include <hip/hip_bf16.h>
#include <stdint.h>

#define D_DIM 1024
#define H_DIM 4096
#define E_NUM 8
#define NTOK  4096   // B*S
#define CAP_E 4096

#define BM 128
#define BN 128
#define BK 64        // bf16 elems per K-tile; LDS row = 128 B = 8 chunks of 16 B

typedef __bf16 bf16x8 __attribute__((ext_vector_type(8)));
typedef float  f32x4  __attribute__((ext_vector_type(4)));

static __device__ __forceinline__ unsigned short f2bf(float f) {
    union { float f; unsigned u; } v; v.f = f;
    unsigned r = v.u + 0x7fffu + ((v.u >> 16) & 1u);   // RNE
    return (unsigned short)(r >> 16);
}

// async global->LDS, 16 B per lane; LDS dest = wave-uniform base + lane*16
static __device__ __forceinline__ void gload16(const unsigned short* g, unsigned short* l) {
    __builtin_amdgcn_global_load_lds(
        (const __attribute__((address_space(1))) unsigned int*)g,
        (__attribute__((address_space(3))) unsigned int*)l,
        16, 0, 0);
}

// exact-erf GELU via Abramowitz-Stegun 7.1.26 (|err| <= 1.5e-7, invisible in bf16)
static __device__ __forceinline__ float gelu_f(float v) {
    const float z = fabsf(v) * 0.70710678118654752f;
    const float t = __builtin_amdgcn_rcpf(__builtin_fmaf(0.3275911f, z, 1.f));
    float p = __builtin_fmaf(1.061405429f, t, -1.453152027f);
    p = __builtin_fmaf(p, t, 1.421413741f);
    p = __builtin_fmaf(p, t, -0.284496736f);
    p = __builtin_fmaf(p, t, 0.254829592f);
    const float e = 1.f - p * t * __expf(-z * z);
    const float erfv = (v < 0.f) ? -e : e;
    return v * (0.5f + 0.5f * erfv);
}

// ---------------- gating: scores -> top2 -> softmax -> expert lists ----------
__global__ __launch_bounds__(256) void gate_kernel(
    const float* __restrict__ x, const float* __restrict__ gw,
    const float* __restrict__ gb, int* __restrict__ counts,
    int* __restrict__ tok_list, float* __restrict__ prob_list)
{
    const int wave = threadIdx.x >> 6, lane = threadIdx.x & 63;
    const int t = blockIdx.x * 4 + wave;
    double s[E_NUM];
#pragma unroll
    for (int j = 0; j < E_NUM; ++j) s[j] = 0.0;
    const float* xr = x + (size_t)t * D_DIM;
#pragma unroll
    for (int i = 0; i < D_DIM / 64; ++i) {
        const int d = i * 64 + lane;
        const float xv = xr[d];
        const float4 g0 = *(const float4*)(gw + d * 8);
        const float4 g1 = *(const float4*)(gw + d * 8 + 4);
        s[0] += (double)xv * g0.x; s[1] += (double)xv * g0.y;
        s[2] += (double)xv * g0.z; s[3] += (double)xv * g0.w;
        s[4] += (double)xv * g1.x; s[5] += (double)xv * g1.y;
        s[6] += (double)xv * g1.z; s[7] += (double)xv * g1.w;
    }
#pragma unroll
    for (int off = 32; off >= 1; off >>= 1)
#pragma unroll
        for (int j = 0; j < E_NUM; ++j) s[j] += __shfl_xor(s[j], off, 64);

    if (lane == 0) {
#pragma unroll
        for (int j = 0; j < E_NUM; ++j) s[j] += (double)gb[j];
        int i0 = 0;
        for (int j = 1; j < E_NUM; ++j) if (s[j] > s[i0]) i0 = j;
        int i1 = (i0 == 0) ? 1 : 0;
        for (int j = 0; j < E_NUM; ++j) if (j != i0 && s[j] > s[i1]) i1 = j;
        const double e1 = exp(s[i1] - s[i0]);
        const float p0 = (float)(1.0 / (1.0 + e1));
        const float p1 = (float)(e1 / (1.0 + e1));
        int pos0 = atomicAdd(&counts[i0], 1);
        tok_list[i0 * CAP_E + pos0]  = t;
        prob_list[i0 * CAP_E + pos0] = p0;
        int pos1 = atomicAdd(&counts[i1], 1);
        tok_list[i1 * CAP_E + pos1]  = t;
        prob_list[i1 * CAP_E + pos1] = p1;
    }
}

__global__ void offsets_kernel(const int* __restrict__ counts, int* __restrict__ offsets) {
    if (threadIdx.x == 0) {
        int acc = 0;
        for (int e = 0; e < E_NUM; ++e) { offsets[e] = acc; acc += counts[e]; }
    }
}

// ---------------- x fp32 -> bf16 ----------------
__global__ __launch_bounds__(256) void xconv_kernel(
    const float* __restrict__ x, unsigned short* __restrict__ xb)
{
    const int i = (blockIdx.x * 256 + threadIdx.x) * 8;
    const float4 a = *(const float4*)(x + i);
    const float4 b = *(const float4*)(x + i + 4);
    uint4 u;
    u.x = (unsigned)f2bf(a.x) | ((unsigned)f2bf(a.y) << 16);
    u.y = (unsigned)f2bf(a.z) | ((unsigned)f2bf(a.w) << 16);
    u.z = (unsigned)f2bf(b.x) | ((unsigned)f2bf(b.y) << 16);
    u.w = (unsigned)f2bf(b.z) | ((unsigned)f2bf(b.w) << 16);
    *(uint4*)(xb + i) = u;
}

// ---------------- weight transpose+convert: in [R][C] fp32 -> out [C][R] bf16
__global__ __launch_bounds__(256) void wtrans_kernel(
    const float* __restrict__ in, unsigned short* __restrict__ out, int R, int C)
{
    __shared__ unsigned tile[64][33];   // [c_local][r_pair]
    const size_t slab = (size_t)blockIdx.z * (size_t)R * C;
    const float* inp = in + slab;
    unsigned short* outp = out + slab;
    const int c0 = blockIdx.x * 64, r0 = blockIdx.y * 64;
    const int tid = threadIdx.x;
    const int cq = tid & 15, p0 = tid >> 4;
#pragma unroll
    for (int s = 0; s < 2; ++s) {
        const int p = p0 + s * 16;          // r-pair index 0..31
        const int r = r0 + 2 * p;
        const int c = c0 + cq * 4;
        const float4 va = *(const float4*)(inp + (size_t)r * C + c);
        const float4 vb = *(const float4*)(inp + (size_t)(r + 1) * C + c);
        const float* fa = (const float*)&va;
        const float* fb = (const float*)&vb;
#pragma unroll
        for (int i = 0; i < 4; ++i)
            tile[cq * 4 + i][p] = (unsigned)f2bf(fa[i]) | ((unsigned)f2bf(fb[i]) << 16);
    }
    __syncthreads();
    const int cl = tid >> 2, q = tid & 3;
#pragma unroll
    for (int s = 0; s < 2; ++s) {
        const int qq = q + s * 4;           // 0..7: covers all 64 rows
        uint4 wv;
        wv.x = tile[cl][qq * 4 + 0]; wv.y = tile[cl][qq * 4 + 1];
        wv.z = tile[cl][qq * 4 + 2]; wv.w = tile[cl][qq * 4 + 3];
        *(uint4*)(outp + (size_t)(c0 + cl) * R + r0 + qq * 8) = wv;
    }
}

// ---------------- FC1: h = gelu(x[toks] @ w1t^T + b1) -> bf16 h_ws ----------
// 1-D grid, XCD-swizzled; 2-phase double-buffered K-loop.
__global__ __launch_bounds__(256) void expert_fc1(
    const unsigned short* __restrict__ xb, const unsigned short* __restrict__ w1t,
    const float* __restrict__ b1, const int* __restrict__ counts,
    const int* __restrict__ offsets, const int* __restrict__ tok_list,
    unsigned short* __restrict__ h_ws,
    int gx, int gxy, int e_param, int we_param, int row_start, int cap, int packed)
{
    __shared__ __align__(16) unsigned short As[2][BM * BK];
    __shared__ __align__(16) unsigned short Bs[2][BN * BK];

    int lin = (int)blockIdx.x;
    const int nwg = (int)gridDim.x;
    if ((nwg & 7) == 0) lin = (lin & 7) * (nwg >> 3) + (lin >> 3);   // XCD chunks
    const int ez  = lin / gxy;
    const int rem = lin - ez * gxy;
    const int by  = rem / gx;
    const int bx  = rem - by * gx;

    const int e = (e_param >= 0) ? e_param : ez;
    const int we = (we_param >= 0) ? we_param : e;
    const int cnt = counts[e];
    const int row_end = min(cnt, row_start + cap);
    const int row0 = row_start + by * BM;
    if (row0 >= row_end) return;
    const int n0 = bx * BN;
    const int hb = packed ? offsets[e] : 0;
    const int tid = threadIdx.x;

    const int wv = tid >> 6, lane = tid & 63;
    const int schunk = (lane & 7) ^ (lane >> 3);     // pre-swizzled source chunk
    const unsigned short* __restrict__ w1e = w1t + (size_t)we * H_DIM * D_DIM;

    const unsigned short* aptr[4];
    const unsigned short* bptr[4];
#pragma unroll
    for (int j = 0; j < 4; ++j) {
        const int r = (wv * 4 + j) * 8 + (lane >> 3);
        const int rr = min(row0 + r, row_end - 1);
        aptr[j] = xb + (size_t)tok_list[e * CAP_E + rr] * D_DIM + schunk * 8;
        bptr[j] = w1e + (size_t)(n0 + r) * D_DIM + schunk * 8;
    }

    const int wr = (wv >> 1) * 64, wc = (wv & 1) * 64;
    const int rl = lane & 15, x7 = lane & 7, kg = lane >> 4;
    int aoff[2][4], boff[2][4];
#pragma unroll
    for (int s = 0; s < 2; ++s) {
        const int slot = ((((s << 2) + kg) ^ x7) << 3);
#pragma unroll
        for (int m = 0; m < 4; ++m) aoff[s][m] = ((wr + m * 16 + rl) << 6) + slot;
#pragma unroll
        for (int n = 0; n < 4; ++n) boff[s][n] = ((wc + n * 16 + rl) << 6) + slot;
    }

    f32x4 acc[4][4];
#pragma unroll
    for (int m = 0; m < 4; ++m)
#pragma unroll
        for (int n = 0; n < 4; ++n) acc[m][n] = (f32x4){0.f, 0.f, 0.f, 0.f};

    // prologue: stage tile 0 into buf 0
#pragma unroll
    for (int j = 0; j < 4; ++j) {
        gload16(aptr[j], &As[0][(wv * 4 + j) * 512]);
        gload16(bptr[j], &Bs[0][(wv * 4 + j) * 512]);
    }
    __syncthreads();                       // implicit vmcnt(0) drain

    const int NT = D_DIM / BK;
    int cur = 0;
    for (int t = 0; t < NT; ++t) {
        if (t + 1 < NT) {                  // prefetch next tile into other buf
            const int kn = (t + 1) * BK;
#pragma unroll
            for (int j = 0; j < 4; ++j) {
                gload16(aptr[j] + kn, &As[cur ^ 1][(wv * 4 + j) * 512]);
                gload16(bptr[j] + kn, &Bs[cur ^ 1][(wv * 4 + j) * 512]);
            }
        }
        const unsigned short* Ac = As[cur];
        const unsigned short* Bc = Bs[cur];
#pragma unroll
        for (int s = 0; s < 2; ++s) {
            bf16x8 af[4], bfv[4];
#pragma unroll
            for (int m = 0; m < 4; ++m) af[m] = *(const bf16x8*)&Ac[aoff[s][m]];
#pragma unroll
            for (int n = 0; n < 4; ++n) bfv[n] = *(const bf16x8*)&Bc[boff[s][n]];
#pragma unroll
            for (int m = 0; m < 4; ++m)
#pragma unroll
                for (int n = 0; n < 4; ++n)
                    acc[m][n] = __builtin_amdgcn_mfma_f32_16x16x32_bf16(af[m], bfv[n], acc[m][n], 0, 0, 0);
        }
        __syncthreads();                   // drains prefetch + protects buf reuse
        cur ^= 1;
    }

    const float* __restrict__ b1e = b1 + e * H_DIM;
    const int crb = (lane >> 4) * 4, ccol = lane & 15;
#pragma unroll
    for (int n = 0; n < 4; ++n) {
        const int gc = n0 + wc + n * 16 + ccol;
        const float bias = b1e[gc];
#pragma unroll
        for (int m = 0; m < 4; ++m) {
#pragma unroll
            for (int j = 0; j < 4; ++j) {
                const int gr = row0 + wr + m * 16 + crb + j;
                if (gr < row_end) {
                    const float v = acc[m][n][j] + bias;
                    h_ws[(size_t)(hb + gr - row_start) * H_DIM + gc] = f2bf(gelu_f(v));
                }
            }
        }
    }
}

// ---------------- FC2: out[tok] += p * (h @ w2t^T + b2) ---------------------
__global__ __launch_bounds__(256) void expert_fc2(
    const unsigned short* __restrict__ h_ws, const unsigned short* __restrict__ w2t,
    const float* __restrict__ b2, const int* __restrict__ counts,
    const int* __restrict__ offsets, const int* __restrict__ tok_list,
    const float* __restrict__ prob_list, float* __restrict__ out,
    int gx, int gxy, int e_param, int we_param, int row_start, int cap, int packed)
{
    __shared__ __align__(16) unsigned short As[2][BM * BK];
    __shared__ __align__(16) unsigned short Bs[2][BN * BK];

    int lin = (int)blockIdx.x;
    const int nwg = (int)gridDim.x;
    if ((nwg & 7) == 0) lin = (lin & 7) * (nwg >> 3) + (lin >> 3);
    const int ez  = lin / gxy;
    const int rem = lin - ez * gxy;
    const int by  = rem / gx;
    const int bx  = rem - by * gx;

    const int e = (e_param >= 0) ? e_param : ez;
    const int we = (we_param >= 0) ? we_param : e;
    const int cnt = counts[e];
    const int row_end = min(cnt, row_start + cap);
    const int row0 = row_start + by * BM;
    if (row0 >= row_end) return;
    const int n0 = bx * BN;
    const int hb = packed ? offsets[e] : 0;
    const int tid = threadIdx.x;

    const int wv = tid >> 6, lane = tid & 63;
    const int schunk = (lane & 7) ^ (lane >> 3);
    const unsigned short* __restrict__ w2e = w2t + (size_t)we * D_DIM * H_DIM;

    const unsigned short* aptr[4];
    const unsigned short* bptr[4];
#pragma unroll
    for (int j = 0; j < 4; ++j) {
        const int rloc = (wv * 4 + j) * 8 + (lane >> 3);
        int r = row0 + rloc; if (r >= row_end) r = row_end - 1;
        aptr[j] = h_ws + (size_t)(hb + r - row_start) * H_DIM + schunk * 8;
        bptr[j] = w2e + (size_t)(n0 + rloc) * H_DIM + schunk * 8;
    }

    const int wr = (wv >> 1) * 64, wc = (wv & 1) * 64;
    const int rl = lane & 15, x7 = lane & 7, kg = lane >> 4;
    int aoff[2][4], boff[2][4];
#pragma unroll
    for (int s = 0; s < 2; ++s) {
        const int slot = ((((s << 2) + kg) ^ x7) << 3);
#pragma unroll
        for (int m = 0; m < 4; ++m) aoff[s][m] = ((wr + m * 16 + rl) << 6) + slot;
#pragma unroll
        for (int n = 0; n < 4; ++n) boff[s][n] = ((wc + n * 16 + rl) << 6) + slot;
    }

    f32x4 acc[4][4];
#pragma unroll
    for (int m = 0; m < 4; ++m)
#pragma unroll
        for (int n = 0; n < 4; ++n) acc[m][n] = (f32x4){0.f, 0.f, 0.f, 0.f};

    // prologue
#pragma unroll
    for (int j = 0; j < 4; ++j) {
        gload16(aptr[j], &As[0][(wv * 4 + j) * 512]);
        gload16(bptr[j], &Bs[0][(wv * 4 + j) * 512]);
    }
    __syncthreads();

    const int NT = H_DIM / BK;
    int cur = 0;
    for (int t = 0; t < NT; ++t) {
        if (t + 1 < NT) {
            const int kn = (t + 1) * BK;
#pragma unroll
            for (int j = 0; j < 4; ++j) {
                gload16(aptr[j] + kn, &As[cur ^ 1][(wv * 4 + j) * 512]);
                gload16(bptr[j] + kn, &Bs[cur ^ 1][(wv * 4 + j) * 512]);
            }
        }
        const unsigned short* Ac = As[cur];
        const unsigned short* Bc = Bs[cur];
#pragma unroll
        for (int s = 0; s < 2; ++s) {
            bf16x8 af[4], bfv[4];
#pragma unroll
            for (int m = 0; m < 4; ++m) af[m] = *(const bf16x8*)&Ac[aoff[s][m]];
#pragma unroll
            for (int n = 0; n < 4; ++n) bfv[n] = *(const bf16x8*)&Bc[boff[s][n]];
#pragma unroll
            for (int m = 0; m < 4; ++m)
#pragma unroll
                for (int n = 0; n < 4; ++n)
                    acc[m][n] = __builtin_amdgcn_mfma_f32_16x16x32_bf16(af[m], bfv[n], acc[m][n], 0, 0, 0);
        }
        __syncthreads();
        cur ^= 1;
    }

    const float* __restrict__ b2e = b2 + e * D_DIM;
    const int crb = (lane >> 4) * 4, ccol = lane & 15;
#pragma unroll
    for (int n = 0; n < 4; ++n) {
        const int gc = n0 + wc + n * 16 + ccol;
        const float bias = b2e[gc];
#pragma unroll
        for (int m = 0; m < 4; ++m) {
#pragma unroll
            for (int j = 0; j < 4; ++j) {
                const int gr = row0 + wr + m * 16 + crb + j;
                if (gr < row_end) {
                    const float yv = acc[m][n][j] + bias;
                    const int t = tok_list[e * CAP_E + gr];
                    const float p = prob_list[e * CAP_E + gr];
                    atomicAdd(&out[(size_t)t * D_DIM + gc], p * yv);
                }
            }
        }
    }
}

extern "C" void kernel_launch(void* const* d_in, const int* in_sizes, int n_in,
                              void* d_out, int out_size, void* d_ws, size_t ws_size,
                              hipStream_t stream)
{
    const float* x  = (const float*)d_in[0];
    const float* w1 = (const float*)d_in[1];
    const float* b1 = (const float*)d_in[2];
    const float* w2 = (const float*)d_in[3];
    const float* b2 = (const float*)d_in[4];
    const float* gw = (const float*)d_in[5];
    const float* gb = (const float*)d_in[6];
    float* out = (float*)d_out;

    char* w = (char*)d_ws;
    int*   counts    = (int*)w;
    int*   offsets   = (int*)(w + 64);
    int*   tok_list  = (int*)(w + 128);
    float* prob_list = (float*)(w + 128 + (size_t)CAP_E * E_NUM * 4);
    size_t off = 128 + 2 * (size_t)CAP_E * E_NUM * 4;
    off = (off + 255) & ~(size_t)255;
    unsigned short* xb = (unsigned short*)(w + off);
    off += (size_t)NTOK * D_DIM * 2;

    const size_t wslab = (size_t)D_DIM * H_DIM * 2;   // bf16 bytes per expert
    const size_t hfull = (size_t)2 * NTOK * H_DIM * 2;
    const size_t need_full = off + 2 * E_NUM * wslab + hfull;

    hipMemsetAsync(d_out, 0, (size_t)out_size * sizeof(float), stream);
    hipMemsetAsync(counts, 0, 64, stream);

    gate_kernel<<<NTOK / 4, 256, 0, stream>>>(x, gw, gb, counts, tok_list, prob_list);
    offsets_kernel<<<1, 64, 0, stream>>>(counts, offsets);
    xconv_kernel<<<NTOK * D_DIM / 2048, 256, 0, stream>>>(x, xb);

    if (ws_size >= need_full) {
        unsigned short* w1t = (unsigned short*)(w + off);
        unsigned short* w2t = (unsigned short*)(w + off + E_NUM * wslab);
        unsigned short* h_ws = (unsigned short*)(w + off + 2 * E_NUM * wslab);
        wtrans_kernel<<<dim3(H_DIM / 64, D_DIM / 64, E_NUM), 256, 0, stream>>>(w1, w1t, D_DIM, H_DIM);
        wtrans_kernel<<<dim3(D_DIM / 64, H_DIM / 64, E_NUM), 256, 0, stream>>>(w2, w2t, H_DIM, D_DIM);
        {
            const int gx = H_DIM / BN, gy = NTOK / BM;
            expert_fc1<<<gx * gy * E_NUM, 256, 0, stream>>>(
                xb, w1t, b1, counts, offsets, tok_list, h_ws,
                gx, gx * gy, -1, -1, 0, NTOK, 1);
        }
        {
            const int gx = D_DIM / BN, gy = NTOK / BM;
            expert_fc2<<<gx * gy * E_NUM, 256, 0, stream>>>(
                h_ws, w2t, b2, counts, offsets, tok_list, prob_list, out,
                gx, gx * gy, -1, -1, 0, NTOK, 1);
        }
    } else {
        // per-expert fallback: convert one expert's weights at a time
        unsigned short* w1te = (unsigned short*)(w + off);
        unsigned short* w2te = (unsigned short*)(w + off + wslab);
        size_t h_off = off + 2 * wslab;
        unsigned short* h_e = (unsigned short*)(w + h_off);
        size_t h_avail = (ws_size > h_off) ? (ws_size - h_off) / ((size_t)H_DIM * 2) : 0;
        int cap = (int)((h_avail < (size_t)NTOK) ? h_avail : (size_t)NTOK);
        cap = (cap / BM) * BM;
        if (cap < BM) cap = BM;
        const int chunks = (NTOK + cap - 1) / cap;
        for (int e = 0; e < E_NUM; ++e) {
            wtrans_kernel<<<dim3(H_DIM / 64, D_DIM / 64, 1), 256, 0, stream>>>(
                w1 + (size_t)e * D_DIM * H_DIM, w1te, D_DIM, H_DIM);
            wtrans_kernel<<<dim3(D_DIM / 64, H_DIM / 64, 1), 256, 0, stream>>>(
                w2 + (size_t)e * H_DIM * D_DIM, w2te, H_DIM, D_DIM);
            for (int c = 0; c < chunks; ++c) {
                const int rs = c * cap;
                const int gy1 = (cap + BM - 1) / BM;
                expert_fc1<<<(H_DIM / BN) * gy1, 256, 0, stream>>>(
                    xb, w1te, b1, counts, offsets, tok_list, h_e,
                    H_DIM / BN, (H_DIM / BN) * gy1, e, 0, rs, cap, 0);
                expert_fc2<<<(D_DIM / BN) * gy1, 256, 0, stream>>>(
                    h_e, w2te, b2, counts, offsets, tok_list, prob_list, out,
                    D_DIM / BN, (D_DIM / BN) * gy1, e, 0, rs, cap, 0);
            }
        }
    }
}

// Round 5
// 539.183 us; speedup vs baseline: 1.0725x; 1.0725x over previous
//
#include <hip/hip_runtime.h>
#include <hip/hip_bf16.h>
#include <stdint.h>

#define D_DIM 1024
#define H_DIM 4096
#define E_NUM 8
#define NTOK  4096   // B*S
#define CAP_E 4096

#define BM 128
#define BN 128
#define BK 64        // bf16 elems per K-tile; LDS row = 128 B = 8 chunks of 16 B

typedef __bf16 bf16x8 __attribute__((ext_vector_type(8)));
typedef float  f32x4  __attribute__((ext_vector_type(4)));

static __device__ __forceinline__ unsigned short f2bf(float f) {
    union { float f; unsigned u; } v; v.f = f;
    unsigned r = v.u + 0x7fffu + ((v.u >> 16) & 1u);   // RNE
    return (unsigned short)(r >> 16);
}

// async global->LDS, 16 B per lane; LDS dest = wave-uniform base + lane*16
static __device__ __forceinline__ void gload16(const unsigned short* g, unsigned short* l) {
    __builtin_amdgcn_global_load_lds(
        (const __attribute__((address_space(1))) unsigned int*)g,
        (__attribute__((address_space(3))) unsigned int*)l,
        16, 0, 0);
}

// exact-erf GELU via Abramowitz-Stegun 7.1.26 (|err| <= 1.5e-7, invisible in bf16)
static __device__ __forceinline__ float gelu_f(float v) {
    const float z = fabsf(v) * 0.70710678118654752f;
    const float t = __builtin_amdgcn_rcpf(__builtin_fmaf(0.3275911f, z, 1.f));
    float p = __builtin_fmaf(1.061405429f, t, -1.453152027f);
    p = __builtin_fmaf(p, t, 1.421413741f);
    p = __builtin_fmaf(p, t, -0.284496736f);
    p = __builtin_fmaf(p, t, 0.254829592f);
    const float e = 1.f - p * t * __expf(-z * z);
    const float erfv = (v < 0.f) ? -e : e;
    return v * (0.5f + 0.5f * erfv);
}

// ---------------- gating: scores -> top2 -> softmax -> expert lists ----------
__global__ __launch_bounds__(256) void gate_kernel(
    const float* __restrict__ x, const float* __restrict__ gw,
    const float* __restrict__ gb, int* __restrict__ counts,
    int* __restrict__ tok_list, float* __restrict__ prob_list)
{
    const int wave = threadIdx.x >> 6, lane = threadIdx.x & 63;
    const int t = blockIdx.x * 4 + wave;
    double s[E_NUM];
#pragma unroll
    for (int j = 0; j < E_NUM; ++j) s[j] = 0.0;
    const float* xr = x + (size_t)t * D_DIM;
#pragma unroll
    for (int i = 0; i < D_DIM / 64; ++i) {
        const int d = i * 64 + lane;
        const float xv = xr[d];
        const float4 g0 = *(const float4*)(gw + d * 8);
        const float4 g1 = *(const float4*)(gw + d * 8 + 4);
        s[0] += (double)xv * g0.x; s[1] += (double)xv * g0.y;
        s[2] += (double)xv * g0.z; s[3] += (double)xv * g0.w;
        s[4] += (double)xv * g1.x; s[5] += (double)xv * g1.y;
        s[6] += (double)xv * g1.z; s[7] += (double)xv * g1.w;
    }
#pragma unroll
    for (int off = 32; off >= 1; off >>= 1)
#pragma unroll
        for (int j = 0; j < E_NUM; ++j) s[j] += __shfl_xor(s[j], off, 64);

    if (lane == 0) {
#pragma unroll
        for (int j = 0; j < E_NUM; ++j) s[j] += (double)gb[j];
        int i0 = 0;
        for (int j = 1; j < E_NUM; ++j) if (s[j] > s[i0]) i0 = j;
        int i1 = (i0 == 0) ? 1 : 0;
        for (int j = 0; j < E_NUM; ++j) if (j != i0 && s[j] > s[i1]) i1 = j;
        const double e1 = exp(s[i1] - s[i0]);
        const float p0 = (float)(1.0 / (1.0 + e1));
        const float p1 = (float)(e1 / (1.0 + e1));
        int pos0 = atomicAdd(&counts[i0], 1);
        tok_list[i0 * CAP_E + pos0]  = t;
        prob_list[i0 * CAP_E + pos0] = p0;
        int pos1 = atomicAdd(&counts[i1], 1);
        tok_list[i1 * CAP_E + pos1]  = t;
        prob_list[i1 * CAP_E + pos1] = p1;
    }
}

__global__ void offsets_kernel(const int* __restrict__ counts, int* __restrict__ offsets) {
    if (threadIdx.x == 0) {
        int acc = 0;
        for (int e = 0; e < E_NUM; ++e) { offsets[e] = acc; acc += counts[e]; }
    }
}

// ---------------- x fp32 -> bf16 ----------------
__global__ __launch_bounds__(256) void xconv_kernel(
    const float* __restrict__ x, unsigned short* __restrict__ xb)
{
    const int i = (blockIdx.x * 256 + threadIdx.x) * 8;
    const float4 a = *(const float4*)(x + i);
    const float4 b = *(const float4*)(x + i + 4);
    uint4 u;
    u.x = (unsigned)f2bf(a.x) | ((unsigned)f2bf(a.y) << 16);
    u.y = (unsigned)f2bf(a.z) | ((unsigned)f2bf(a.w) << 16);
    u.z = (unsigned)f2bf(b.x) | ((unsigned)f2bf(b.y) << 16);
    u.w = (unsigned)f2bf(b.z) | ((unsigned)f2bf(b.w) << 16);
    *(uint4*)(xb + i) = u;
}

// ---------------- weight transpose+convert: in [R][C] fp32 -> out [C][R] bf16
__global__ __launch_bounds__(256) void wtrans_kernel(
    const float* __restrict__ in, unsigned short* __restrict__ out, int R, int C)
{
    __shared__ unsigned tile[64][33];   // [c_local][r_pair]
    const size_t slab = (size_t)blockIdx.z * (size_t)R * C;
    const float* inp = in + slab;
    unsigned short* outp = out + slab;
    const int c0 = blockIdx.x * 64, r0 = blockIdx.y * 64;
    const int tid = threadIdx.x;
    const int cq = tid & 15, p0 = tid >> 4;
#pragma unroll
    for (int s = 0; s < 2; ++s) {
        const int p = p0 + s * 16;          // r-pair index 0..31
        const int r = r0 + 2 * p;
        const int c = c0 + cq * 4;
        const float4 va = *(const float4*)(inp + (size_t)r * C + c);
        const float4 vb = *(const float4*)(inp + (size_t)(r + 1) * C + c);
        const float* fa = (const float*)&va;
        const float* fb = (const float*)&vb;
#pragma unroll
        for (int i = 0; i < 4; ++i)
            tile[cq * 4 + i][p] = (unsigned)f2bf(fa[i]) | ((unsigned)f2bf(fb[i]) << 16);
    }
    __syncthreads();
    const int cl = tid >> 2, q = tid & 3;
#pragma unroll
    for (int s = 0; s < 2; ++s) {
        const int qq = q + s * 4;           // 0..7: covers all 64 rows
        uint4 wv;
        wv.x = tile[cl][qq * 4 + 0]; wv.y = tile[cl][qq * 4 + 1];
        wv.z = tile[cl][qq * 4 + 2]; wv.w = tile[cl][qq * 4 + 3];
        *(uint4*)(outp + (size_t)(c0 + cl) * R + r0 + qq * 8) = wv;
    }
}

// ---------------- FC1: h = gelu(x[toks] @ w1t^T + b1) -> bf16 h_ws ----------
// grid 1-D, bx-fastest (bx&7 -> XCD): bx = (bid&7) + ((bid>>3)&3)*8, gy from arg.
// Single-buffer 32 KB LDS -> 5 blocks/CU co-residency.
__global__ __launch_bounds__(256) void expert_fc1(
    const unsigned short* __restrict__ xb, const unsigned short* __restrict__ w1t,
    const float* __restrict__ b1, const int* __restrict__ counts,
    const int* __restrict__ offsets, const int* __restrict__ tok_list,
    unsigned short* __restrict__ h_ws,
    int gy, int e_param, int we_param, int row_start, int cap, int packed)
{
    __shared__ __align__(16) unsigned short As[BM * BK];
    __shared__ __align__(16) unsigned short Bs[BN * BK];

    int r0d = (int)blockIdx.x;
    const int bxl = r0d & 7; r0d >>= 3;
    const int bxh = r0d & 3; r0d >>= 2;
    const int by  = r0d % gy;
    const int ez  = r0d / gy;
    const int bx  = bxh * 8 + bxl;          // 0..31

    const int e = (e_param >= 0) ? e_param : ez;
    const int we = (we_param >= 0) ? we_param : e;
    const int cnt = counts[e];
    const int row_end = min(cnt, row_start + cap);
    const int row0 = row_start + by * BM;
    if (row0 >= row_end) return;
    const int n0 = bx * BN;
    const int hb = packed ? offsets[e] : 0;
    const int tid = threadIdx.x;

    const int wv = tid >> 6, lane = tid & 63;
    const int schunk = (lane & 7) ^ (lane >> 3);     // pre-swizzled source chunk
    const unsigned short* __restrict__ w1e = w1t + (size_t)we * H_DIM * D_DIM;

    const unsigned short* aptr[4];
    const unsigned short* bptr[4];
#pragma unroll
    for (int j = 0; j < 4; ++j) {
        const int r = (wv * 4 + j) * 8 + (lane >> 3);
        const int rr = min(row0 + r, row_end - 1);
        aptr[j] = xb + (size_t)tok_list[e * CAP_E + rr] * D_DIM + schunk * 8;
        bptr[j] = w1e + (size_t)(n0 + r) * D_DIM + schunk * 8;
    }

    const int wr = (wv >> 1) * 64, wc = (wv & 1) * 64;
    const int rl = lane & 15, x7 = lane & 7, kg = lane >> 4;
    int aoff[2][4], boff[2][4];
#pragma unroll
    for (int s = 0; s < 2; ++s) {
        const int slot = ((((s << 2) + kg) ^ x7) << 3);
#pragma unroll
        for (int m = 0; m < 4; ++m) aoff[s][m] = ((wr + m * 16 + rl) << 6) + slot;
#pragma unroll
        for (int n = 0; n < 4; ++n) boff[s][n] = ((wc + n * 16 + rl) << 6) + slot;
    }

    f32x4 acc[4][4];
#pragma unroll
    for (int m = 0; m < 4; ++m)
#pragma unroll
        for (int n = 0; n < 4; ++n) acc[m][n] = (f32x4){0.f, 0.f, 0.f, 0.f};

    for (int kk = 0; kk < D_DIM; kk += BK) {
        __syncthreads();   // previous tile fully consumed
#pragma unroll
        for (int j = 0; j < 4; ++j) {
            gload16(aptr[j] + kk, &As[(wv * 4 + j) * 512]);
            gload16(bptr[j] + kk, &Bs[(wv * 4 + j) * 512]);
        }
        __syncthreads();   // staged (vmcnt drained at barrier)
#pragma unroll
        for (int s = 0; s < 2; ++s) {
            bf16x8 af[4], bfv[4];
#pragma unroll
            for (int m = 0; m < 4; ++m) af[m] = *(const bf16x8*)&As[aoff[s][m]];
#pragma unroll
            for (int n = 0; n < 4; ++n) bfv[n] = *(const bf16x8*)&Bs[boff[s][n]];
#pragma unroll
            for (int m = 0; m < 4; ++m)
#pragma unroll
                for (int n = 0; n < 4; ++n)
                    acc[m][n] = __builtin_amdgcn_mfma_f32_16x16x32_bf16(af[m], bfv[n], acc[m][n], 0, 0, 0);
        }
    }

    const float* __restrict__ b1e = b1 + e * H_DIM;
    const int crb = (lane >> 4) * 4, ccol = lane & 15;
#pragma unroll
    for (int n = 0; n < 4; ++n) {
        const int gc = n0 + wc + n * 16 + ccol;
        const float bias = b1e[gc];
#pragma unroll
        for (int m = 0; m < 4; ++m) {
#pragma unroll
            for (int j = 0; j < 4; ++j) {
                const int gr = row0 + wr + m * 16 + crb + j;
                if (gr < row_end) {
                    const float v = acc[m][n][j] + bias;
                    h_ws[(size_t)(hb + gr - row_start) * H_DIM + gc] = f2bf(gelu_f(v));
                }
            }
        }
    }
}

// ---------------- FC2: out[tok] += p * (h @ w2t^T + b2), split-K ------------
// bid decode: bx = bid&7 (XCD stripe); by = (bid>>3)%gy; ks; e.
__global__ __launch_bounds__(256) void expert_fc2(
    const unsigned short* __restrict__ h_ws, const unsigned short* __restrict__ w2t,
    const float* __restrict__ b2, const int* __restrict__ counts,
    const int* __restrict__ offsets, const int* __restrict__ tok_list,
    const float* __restrict__ prob_list, float* __restrict__ out,
    int gy, int splitk, int e_param, int we_param, int row_start, int cap, int packed)
{
    __shared__ __align__(16) unsigned short As[BM * BK];
    __shared__ __align__(16) unsigned short Bs[BN * BK];

    int r0d = (int)blockIdx.x;
    const int bx = r0d & 7; r0d >>= 3;
    const int by = r0d % gy; r0d /= gy;
    const int ks = r0d % splitk;
    const int ez = r0d / splitk;

    const int e = (e_param >= 0) ? e_param : ez;
    const int we = (we_param >= 0) ? we_param : e;
    const int cnt = counts[e];
    const int row_end = min(cnt, row_start + cap);
    const int row0 = row_start + by * BM;
    if (row0 >= row_end) return;
    const int n0 = bx * BN;
    const int hb = packed ? offsets[e] : 0;
    const int tid = threadIdx.x;

    const int kspan = H_DIM / splitk;
    const int k0 = ks * kspan;

    const int wv = tid >> 6, lane = tid & 63;
    const int schunk = (lane & 7) ^ (lane >> 3);
    const unsigned short* __restrict__ w2e = w2t + (size_t)we * D_DIM * H_DIM;

    const unsigned short* aptr[4];
    const unsigned short* bptr[4];
#pragma unroll
    for (int j = 0; j < 4; ++j) {
        const int rloc = (wv * 4 + j) * 8 + (lane >> 3);
        int r = row0 + rloc; if (r >= row_end) r = row_end - 1;
        aptr[j] = h_ws + (size_t)(hb + r - row_start) * H_DIM + schunk * 8;
        bptr[j] = w2e + (size_t)(n0 + rloc) * H_DIM + schunk * 8;
    }

    const int wr = (wv >> 1) * 64, wc = (wv & 1) * 64;
    const int rl = lane & 15, x7 = lane & 7, kg = lane >> 4;
    int aoff[2][4], boff[2][4];
#pragma unroll
    for (int s = 0; s < 2; ++s) {
        const int slot = ((((s << 2) + kg) ^ x7) << 3);
#pragma unroll
        for (int m = 0; m < 4; ++m) aoff[s][m] = ((wr + m * 16 + rl) << 6) + slot;
#pragma unroll
        for (int n = 0; n < 4; ++n) boff[s][n] = ((wc + n * 16 + rl) << 6) + slot;
    }

    f32x4 acc[4][4];
#pragma unroll
    for (int m = 0; m < 4; ++m)
#pragma unroll
        for (int n = 0; n < 4; ++n) acc[m][n] = (f32x4){0.f, 0.f, 0.f, 0.f};

    for (int kk = k0; kk < k0 + kspan; kk += BK) {
        __syncthreads();
#pragma unroll
        for (int j = 0; j < 4; ++j) {
            gload16(aptr[j] + kk, &As[(wv * 4 + j) * 512]);
            gload16(bptr[j] + kk, &Bs[(wv * 4 + j) * 512]);
        }
        __syncthreads();
#pragma unroll
        for (int s = 0; s < 2; ++s) {
            bf16x8 af[4], bfv[4];
#pragma unroll
            for (int m = 0; m < 4; ++m) af[m] = *(const bf16x8*)&As[aoff[s][m]];
#pragma unroll
            for (int n = 0; n < 4; ++n) bfv[n] = *(const bf16x8*)&Bs[boff[s][n]];
#pragma unroll
            for (int m = 0; m < 4; ++m)
#pragma unroll
                for (int n = 0; n < 4; ++n)
                    acc[m][n] = __builtin_amdgcn_mfma_f32_16x16x32_bf16(af[m], bfv[n], acc[m][n], 0, 0, 0);
        }
    }

    const float* __restrict__ b2e = b2 + e * D_DIM;
    const int crb = (lane >> 4) * 4, ccol = lane & 15;
#pragma unroll
    for (int n = 0; n < 4; ++n) {
        const int gc = n0 + wc + n * 16 + ccol;
        const float bias = (ks == 0) ? b2e[gc] : 0.f;   // bias added once per output
#pragma unroll
        for (int m = 0; m < 4; ++m) {
#pragma unroll
            for (int j = 0; j < 4; ++j) {
                const int gr = row0 + wr + m * 16 + crb + j;
                if (gr < row_end) {
                    const float yv = acc[m][n][j] + bias;
                    const int t = tok_list[e * CAP_E + gr];
                    const float p = prob_list[e * CAP_E + gr];
                    atomicAdd(&out[(size_t)t * D_DIM + gc], p * yv);
                }
            }
        }
    }
}

extern "C" void kernel_launch(void* const* d_in, const int* in_sizes, int n_in,
                              void* d_out, int out_size, void* d_ws, size_t ws_size,
                              hipStream_t stream)
{
    const float* x  = (const float*)d_in[0];
    const float* w1 = (const float*)d_in[1];
    const float* b1 = (const float*)d_in[2];
    const float* w2 = (const float*)d_in[3];
    const float* b2 = (const float*)d_in[4];
    const float* gw = (const float*)d_in[5];
    const float* gb = (const float*)d_in[6];
    float* out = (float*)d_out;

    char* w = (char*)d_ws;
    int*   counts    = (int*)w;
    int*   offsets   = (int*)(w + 64);
    int*   tok_list  = (int*)(w + 128);
    float* prob_list = (float*)(w + 128 + (size_t)CAP_E * E_NUM * 4);
    size_t off = 128 + 2 * (size_t)CAP_E * E_NUM * 4;
    off = (off + 255) & ~(size_t)255;
    unsigned short* xb = (unsigned short*)(w + off);
    off += (size_t)NTOK * D_DIM * 2;

    const size_t wslab = (size_t)D_DIM * H_DIM * 2;   // bf16 bytes per expert
    const size_t hfull = (size_t)2 * NTOK * H_DIM * 2;
    const size_t need_full = off + 2 * E_NUM * wslab + hfull;

    hipMemsetAsync(d_out, 0, (size_t)out_size * sizeof(float), stream);
    hipMemsetAsync(counts, 0, 64, stream);

    gate_kernel<<<NTOK / 4, 256, 0, stream>>>(x, gw, gb, counts, tok_list, prob_list);
    offsets_kernel<<<1, 64, 0, stream>>>(counts, offsets);
    xconv_kernel<<<NTOK * D_DIM / 2048, 256, 0, stream>>>(x, xb);

    if (ws_size >= need_full) {
        unsigned short* w1t = (unsigned short*)(w + off);
        unsigned short* w2t = (unsigned short*)(w + off + E_NUM * wslab);
        unsigned short* h_ws = (unsigned short*)(w + off + 2 * E_NUM * wslab);
        wtrans_kernel<<<dim3(H_DIM / 64, D_DIM / 64, E_NUM), 256, 0, stream>>>(w1, w1t, D_DIM, H_DIM);
        wtrans_kernel<<<dim3(D_DIM / 64, H_DIM / 64, E_NUM), 256, 0, stream>>>(w2, w2t, H_DIM, D_DIM);
        {
            const int gy = NTOK / BM;   // 32
            expert_fc1<<<32 * gy * E_NUM, 256, 0, stream>>>(
                xb, w1t, b1, counts, offsets, tok_list, h_ws,
                gy, -1, -1, 0, NTOK, 1);
        }
        {
            const int gy = NTOK / BM, sk = 2;
            expert_fc2<<<8 * gy * sk * E_NUM, 256, 0, stream>>>(
                h_ws, w2t, b2, counts, offsets, tok_list, prob_list, out,
                gy, sk, -1, -1, 0, NTOK, 1);
        }
    } else {
        // per-expert fallback: convert one expert's weights at a time
        unsigned short* w1te = (unsigned short*)(w + off);
        unsigned short* w2te = (unsigned short*)(w + off + wslab);
        size_t h_off = off + 2 * wslab;
        unsigned short* h_e = (unsigned short*)(w + h_off);
        size_t h_avail = (ws_size > h_off) ? (ws_size - h_off) / ((size_t)H_DIM * 2) : 0;
        int cap = (int)((h_avail < (size_t)NTOK) ? h_avail : (size_t)NTOK);
        cap = (cap / BM) * BM;
        if (cap < BM) cap = BM;
        const int chunks = (NTOK + cap - 1) / cap;
        for (int e = 0; e < E_NUM; ++e) {
            wtrans_kernel<<<dim3(H_DIM / 64, D_DIM / 64, 1), 256, 0, stream>>>(
                w1 + (size_t)e * D_DIM * H_DIM, w1te, D_DIM, H_DIM);
            wtrans_kernel<<<dim3(D_DIM / 64, H_DIM / 64, 1), 256, 0, stream>>>(
                w2 + (size_t)e * H_DIM * D_DIM, w2te, H_DIM, D_DIM);
            for (int c = 0; c < chunks; ++c) {
                const int rs = c * cap;
                const int gy1 = (cap + BM - 1) / BM;
                expert_fc1<<<32 * gy1, 256, 0, stream>>>(
                    xb, w1te, b1, counts, offsets, tok_list, h_e,
                    gy1, e, 0, rs, cap, 0);
                expert_fc2<<<8 * gy1, 256, 0, stream>>>(
                    h_e, w2te, b2, counts, offsets, tok_list, prob_list, out,
                    gy1, 1, e, 0, rs, cap, 0);
            }
        }
    }
}